// Round 1
// baseline (198.241 us; speedup 1.0000x reference)
//
#include <hip/hip_runtime.h>

#define NN 131072
#define CIN 256
#define CB 64
#define KNB 27

typedef __attribute__((ext_vector_type(8))) short short8_t;   // 8 x bf16 (4 VGPRs)
typedef __attribute__((ext_vector_type(4))) float f32x4;

__device__ inline unsigned short f2bf(float f) {
    union { float f; unsigned u; } x; x.f = f;
    unsigned r = x.u + 0x7fffu + ((x.u >> 16) & 1u);   // round-to-nearest-even
    return (unsigned short)(r >> 16);
}

__device__ inline f32x4 mfma16(short8_t a, short8_t b, f32x4 c) {
    return __builtin_amdgcn_mfma_f32_16x16x32_bf16(a, b, c, 0, 0, 0);
}

// ---------------------------------------------------------------------------
// prep: fold BN into weights, convert to bf16, pre-swizzle into MFMA B-frag
// layout: flat index = ((kstep*4 + coltile)*64 + lane)*8 + j
//   where B-frag element = W[k = kstep*32 + (lane>>4)*8 + j][col = coltile*16 + (lane&15)]
// ---------------------------------------------------------------------------
__global__ __launch_bounds__(256) void prep_kernel(
    const float* __restrict__ w1, const float* __restrict__ w3, const float* __restrict__ w2,
    const float* __restrict__ g1, const float* __restrict__ b1, const float* __restrict__ m1, const float* __restrict__ v1,
    const float* __restrict__ g2, const float* __restrict__ b2, const float* __restrict__ m2, const float* __restrict__ v2,
    const float* __restrict__ g3, const float* __restrict__ b3, const float* __restrict__ m3, const float* __restrict__ v3,
    unsigned short* __restrict__ w1p, unsigned short* __restrict__ w3p, unsigned short* __restrict__ w2p,
    float* __restrict__ bias1, float* __restrict__ bias2, float* __restrict__ bias3)
{
    int t = blockIdx.x * 256 + threadIdx.x;
    if (t < 16384) {                          // w1p: [s:8][t:4][lane:64][j:8], K=256, N=64
        int j = t & 7, lane = (t >> 3) & 63, tt = (t >> 9) & 3, s = t >> 11;
        int c = s * 32 + (lane >> 4) * 8 + j;
        int d = tt * 16 + (lane & 15);
        float sc = g1[d] * rsqrtf(v1[d] + 1e-5f);
        w1p[t] = f2bf(w1[c * CB + d] * sc);
    } else if (t < 16384 + 110592) {          // w3p: [k:27][s:2][t:4][lane:64][j:8]
        int u = t - 16384;
        int j = u & 7, lane = (u >> 3) & 63, tt = (u >> 9) & 3, s = (u >> 11) & 1, k = u >> 12;
        int c = s * 32 + (lane >> 4) * 8 + j;
        int d = tt * 16 + (lane & 15);
        float sc = g2[d] * rsqrtf(v2[d] + 1e-5f);
        w3p[u] = f2bf(w3[(k * CB + c) * CB + d] * sc);
    } else if (t < 143360) {                  // w2p: [s:2][ct:16][lane:64][j:8], K=64, N=256
        int u = t - 126976;
        int j = u & 7, lane = (u >> 3) & 63, ct = (u >> 9) & 15, s = u >> 13;
        int c = s * 32 + (lane >> 4) * 8 + j;
        int d = ct * 16 + (lane & 15);
        float sc = g3[d] * rsqrtf(v3[d] + 1e-5f);
        w2p[u] = f2bf(w2[c * CIN + d] * sc);
    } else if (t < 143744) {                  // biases
        int u = t - 143360;
        if (u < 64)       { float sc = g1[u] * rsqrtf(v1[u] + 1e-5f); bias1[u] = b1[u] - m1[u] * sc; }
        else if (u < 128) { int d = u - 64;  float sc = g2[d] * rsqrtf(v2[d] + 1e-5f); bias2[d] = b2[d] - m2[d] * sc; }
        else              { int d = u - 128; float sc = g3[d] * rsqrtf(v3[d] + 1e-5f); bias3[d] = b3[d] - m3[d] * sc; }
    }
}

// ---------------------------------------------------------------------------
// k1: c1 = relu(data @ w1' + bias1), output bf16 [N,64]
// block = 128 rows, 4 waves x 32 rows; K=256 in 8 steps of 32
// ---------------------------------------------------------------------------
__global__ __launch_bounds__(256) void k1_conv1x1a(
    const float* __restrict__ data, const unsigned short* __restrict__ w1p,
    const float* __restrict__ bias1, unsigned short* __restrict__ c1b)
{
    __shared__ short8_t w1s[2048];   // 32 KB
    int tid = threadIdx.x;
    const short8_t* wsrc = (const short8_t*)w1p;
#pragma unroll
    for (int i = 0; i < 8; i++) w1s[tid + i * 256] = wsrc[tid + i * 256];

    int lane = tid & 63, wave = tid >> 6;
    int g = lane >> 4, r = lane & 15;
    int rowbase = blockIdx.x * 128 + wave * 32;
    f32x4 acc[2][4] = {};
    __syncthreads();

#pragma unroll
    for (int s = 0; s < 8; s++) {
        short8_t a[2];
#pragma unroll
        for (int sub = 0; sub < 2; sub++) {
            const float* ap = data + (size_t)(rowbase + sub * 16 + r) * CIN + s * 32 + g * 8;
            float4 f0 = *(const float4*)ap;
            float4 f1 = *(const float4*)(ap + 4);
            short8_t av;
            av[0] = (short)f2bf(f0.x); av[1] = (short)f2bf(f0.y);
            av[2] = (short)f2bf(f0.z); av[3] = (short)f2bf(f0.w);
            av[4] = (short)f2bf(f1.x); av[5] = (short)f2bf(f1.y);
            av[6] = (short)f2bf(f1.z); av[7] = (short)f2bf(f1.w);
            a[sub] = av;
        }
#pragma unroll
        for (int t = 0; t < 4; t++) {
            short8_t b = w1s[(s * 4 + t) * 64 + lane];
            acc[0][t] = mfma16(a[0], b, acc[0][t]);
            acc[1][t] = mfma16(a[1], b, acc[1][t]);
        }
    }

#pragma unroll
    for (int sub = 0; sub < 2; sub++)
#pragma unroll
        for (int t = 0; t < 4; t++) {
            int col = t * 16 + r;
            float bs = bias1[col];
#pragma unroll
            for (int i = 0; i < 4; i++) {
                int row = rowbase + sub * 16 + g * 4 + i;
                c1b[row * CB + col] = f2bf(fmaxf(acc[sub][t][i] + bs, 0.f));
            }
        }
}

// ---------------------------------------------------------------------------
// k2: c2 = relu(sum_k c1[neigh[n,k]] @ w3'[k] + bias2), bf16 [N,64]
// block = 128 rows, 4 waves x 32 rows; per k: stage 8KB w3 slice in LDS,
// A gathered directly from global (lane loads 16B of the neighbor row)
// ---------------------------------------------------------------------------
__global__ __launch_bounds__(256) void k2_conv3x3(
    const unsigned short* __restrict__ c1b, const int* __restrict__ neigh,
    const unsigned short* __restrict__ w3p, const float* __restrict__ bias2,
    unsigned short* __restrict__ c2b)
{
    __shared__ short8_t w3s[512];    // 8 KB (one k-slice)
    int tid = threadIdx.x;
    int lane = tid & 63, wave = tid >> 6;
    int g = lane >> 4, r = lane & 15;
    int rowbase = blockIdx.x * 128 + wave * 32;
    int n0 = rowbase + r, n1 = rowbase + 16 + r;
    f32x4 acc[2][4] = {};

    for (int k = 0; k < KNB; k++) {
        __syncthreads();    // protect previous iteration's LDS reads
        const short8_t* src = (const short8_t*)(w3p + k * 4096);
        w3s[tid]       = src[tid];
        w3s[tid + 256] = src[tid + 256];

        int idx0 = neigh[n0 * KNB + k];
        int idx1 = neigh[n1 * KNB + k];
        const short8_t* ap0 = (const short8_t*)(c1b + (size_t)idx0 * CB);
        const short8_t* ap1 = (const short8_t*)(c1b + (size_t)idx1 * CB);
        short8_t a0s0 = ap0[g], a0s1 = ap0[4 + g];
        short8_t a1s0 = ap1[g], a1s1 = ap1[4 + g];
        __syncthreads();

#pragma unroll
        for (int t = 0; t < 4; t++) {
            short8_t b0 = w3s[t * 64 + lane];          // s=0
            short8_t b1 = w3s[(4 + t) * 64 + lane];    // s=1
            acc[0][t] = mfma16(a0s0, b0, acc[0][t]);
            acc[1][t] = mfma16(a1s0, b0, acc[1][t]);
            acc[0][t] = mfma16(a0s1, b1, acc[0][t]);
            acc[1][t] = mfma16(a1s1, b1, acc[1][t]);
        }
    }

#pragma unroll
    for (int sub = 0; sub < 2; sub++)
#pragma unroll
        for (int t = 0; t < 4; t++) {
            int col = t * 16 + r;
            float bs = bias2[col];
#pragma unroll
            for (int i = 0; i < 4; i++) {
                int row = rowbase + sub * 16 + g * 4 + i;
                c2b[row * CB + col] = f2bf(fmaxf(acc[sub][t][i] + bs, 0.f));
            }
        }
}

// ---------------------------------------------------------------------------
// k3: out = relu(c2 @ w2' + bias3 + data), fp32 [N,256]
// block = 64 rows x 256 cols; wave w owns cols [w*64, w*64+64)
// ---------------------------------------------------------------------------
__global__ __launch_bounds__(256) void k3_conv1x1b(
    const unsigned short* __restrict__ c2b, const unsigned short* __restrict__ w2p,
    const float* __restrict__ bias3, const float* __restrict__ data,
    float* __restrict__ out)
{
    __shared__ short8_t w2s[2048];   // 32 KB
    int tid = threadIdx.x;
    const short8_t* wsrc = (const short8_t*)w2p;
#pragma unroll
    for (int i = 0; i < 8; i++) w2s[tid + i * 256] = wsrc[tid + i * 256];

    int lane = tid & 63, wave = tid >> 6;
    int g = lane >> 4, r = lane & 15;
    int rowbase = blockIdx.x * 64;

    short8_t a[4][2];
#pragma unroll
    for (int sub = 0; sub < 4; sub++) {
        const short8_t* ap = (const short8_t*)(c2b + (size_t)(rowbase + sub * 16 + r) * CB);
        a[sub][0] = ap[g];
        a[sub][1] = ap[4 + g];
    }
    f32x4 acc[4][4] = {};
    __syncthreads();

#pragma unroll
    for (int s = 0; s < 2; s++)
#pragma unroll
        for (int t = 0; t < 4; t++) {
            short8_t b = w2s[(s * 16 + wave * 4 + t) * 64 + lane];
#pragma unroll
            for (int sub = 0; sub < 4; sub++)
                acc[sub][t] = mfma16(a[sub][s], b, acc[sub][t]);
        }

#pragma unroll
    for (int sub = 0; sub < 4; sub++)
#pragma unroll
        for (int t = 0; t < 4; t++) {
            int col = (wave * 4 + t) * 16 + r;
            float bs = bias3[col];
#pragma unroll
            for (int i = 0; i < 4; i++) {
                int row = rowbase + sub * 16 + g * 4 + i;
                size_t o = (size_t)row * CIN + col;
                out[o] = fmaxf(acc[sub][t][i] + bs + data[o], 0.f);
            }
        }
}

extern "C" void kernel_launch(void* const* d_in, const int* in_sizes, int n_in,
                              void* d_out, int out_size, void* d_ws, size_t ws_size,
                              hipStream_t stream)
{
    const float* data = (const float*)d_in[0];
    const int* neigh  = (const int*)d_in[1];
    const float* w1 = (const float*)d_in[3];
    const float* g1 = (const float*)d_in[4];
    const float* b1 = (const float*)d_in[5];
    const float* m1 = (const float*)d_in[6];
    const float* v1 = (const float*)d_in[7];
    const float* w3 = (const float*)d_in[8];
    const float* g2 = (const float*)d_in[9];
    const float* b2 = (const float*)d_in[10];
    const float* m2 = (const float*)d_in[11];
    const float* v2 = (const float*)d_in[12];
    const float* w2 = (const float*)d_in[13];
    const float* g3 = (const float*)d_in[14];
    const float* b3 = (const float*)d_in[15];
    const float* m3 = (const float*)d_in[16];
    const float* v3 = (const float*)d_in[17];
    float* out = (float*)d_out;

    char* ws = (char*)d_ws;
    // ws layout (needs ~33.9 MB):
    unsigned short* c1b = (unsigned short*)ws;                              // 16 MB
    unsigned short* c2b = (unsigned short*)(ws + 16777216);                 // 16 MB
    unsigned short* w1p = (unsigned short*)(ws + 33554432);                 // 32 KB
    unsigned short* w3p = (unsigned short*)(ws + 33554432 + 32768);         // 216 KB
    unsigned short* w2p = (unsigned short*)(ws + 33554432 + 32768 + 221184);// 32 KB
    float* bias1 = (float*)(ws + 33554432 + 32768 + 221184 + 32768);
    float* bias2 = bias1 + 64;
    float* bias3 = bias1 + 128;

    int n = in_sizes[0] / CIN;   // 131072

    hipLaunchKernelGGL(prep_kernel, dim3(562), dim3(256), 0, stream,
                       w1, w3, w2, g1, b1, m1, v1, g2, b2, m2, v2, g3, b3, m3, v3,
                       w1p, w3p, w2p, bias1, bias2, bias3);
    hipLaunchKernelGGL(k1_conv1x1a, dim3(n / 128), dim3(256), 0, stream, data, w1p, bias1, c1b);
    hipLaunchKernelGGL(k2_conv3x3,  dim3(n / 128), dim3(256), 0, stream, c1b, neigh, w3p, bias2, c2b);
    hipLaunchKernelGGL(k3_conv1x1b, dim3(n / 64),  dim3(256), 0, stream, c2b, w2p, bias3, data, out);
}

// Round 2
// 172.526 us; speedup vs baseline: 1.1490x; 1.1490x over previous
//
#include <hip/hip_runtime.h>

#define NN 131072
#define CIN 256
#define CB 64
#define KNB 27

typedef __attribute__((ext_vector_type(8))) short short8_t;   // 8 x bf16 (4 VGPRs)
typedef __attribute__((ext_vector_type(4))) float f32x4;

__device__ inline unsigned short f2bf(float f) {
    union { float f; unsigned u; } x; x.f = f;
    unsigned r = x.u + 0x7fffu + ((x.u >> 16) & 1u);   // round-to-nearest-even
    return (unsigned short)(r >> 16);
}

__device__ inline f32x4 mfma16(short8_t a, short8_t b, f32x4 c) {
    return __builtin_amdgcn_mfma_f32_16x16x32_bf16(a, b, c, 0, 0, 0);
}

// ---------------------------------------------------------------------------
// prep: fold BN into weights, convert to bf16, pre-swizzle into MFMA B-frag
// layout: flat index = ((kstep*4 + coltile)*64 + lane)*8 + j
//   where B-frag element = W[k = kstep*32 + (lane>>4)*8 + j][col = coltile*16 + (lane&15)]
// ---------------------------------------------------------------------------
__global__ __launch_bounds__(256) void prep_kernel(
    const float* __restrict__ w1, const float* __restrict__ w3, const float* __restrict__ w2,
    const float* __restrict__ g1, const float* __restrict__ b1, const float* __restrict__ m1, const float* __restrict__ v1,
    const float* __restrict__ g2, const float* __restrict__ b2, const float* __restrict__ m2, const float* __restrict__ v2,
    const float* __restrict__ g3, const float* __restrict__ b3, const float* __restrict__ m3, const float* __restrict__ v3,
    unsigned short* __restrict__ w1p, unsigned short* __restrict__ w3p, unsigned short* __restrict__ w2p,
    float* __restrict__ bias1, float* __restrict__ bias2, float* __restrict__ bias3)
{
    int t = blockIdx.x * 256 + threadIdx.x;
    if (t < 16384) {                          // w1p: [s:8][t:4][lane:64][j:8], K=256, N=64
        int j = t & 7, lane = (t >> 3) & 63, tt = (t >> 9) & 3, s = t >> 11;
        int c = s * 32 + (lane >> 4) * 8 + j;
        int d = tt * 16 + (lane & 15);
        float sc = g1[d] * rsqrtf(v1[d] + 1e-5f);
        w1p[t] = f2bf(w1[c * CB + d] * sc);
    } else if (t < 16384 + 110592) {          // w3p: [k:27][s:2][t:4][lane:64][j:8]
        int u = t - 16384;
        int j = u & 7, lane = (u >> 3) & 63, tt = (u >> 9) & 3, s = (u >> 11) & 1, k = u >> 12;
        int c = s * 32 + (lane >> 4) * 8 + j;
        int d = tt * 16 + (lane & 15);
        float sc = g2[d] * rsqrtf(v2[d] + 1e-5f);
        w3p[u] = f2bf(w3[(k * CB + c) * CB + d] * sc);
    } else if (t < 143360) {                  // w2p: [s:2][ct:16][lane:64][j:8], K=64, N=256
        int u = t - 126976;
        int j = u & 7, lane = (u >> 3) & 63, ct = (u >> 9) & 15, s = u >> 13;
        int c = s * 32 + (lane >> 4) * 8 + j;
        int d = ct * 16 + (lane & 15);
        float sc = g3[d] * rsqrtf(v3[d] + 1e-5f);
        w2p[u] = f2bf(w2[c * CIN + d] * sc);
    } else if (t < 143744) {                  // biases
        int u = t - 143360;
        if (u < 64)       { float sc = g1[u] * rsqrtf(v1[u] + 1e-5f); bias1[u] = b1[u] - m1[u] * sc; }
        else if (u < 128) { int d = u - 64;  float sc = g2[d] * rsqrtf(v2[d] + 1e-5f); bias2[d] = b2[d] - m2[d] * sc; }
        else              { int d = u - 128; float sc = g3[d] * rsqrtf(v3[d] + 1e-5f); bias3[d] = b3[d] - m3[d] * sc; }
    }
}

// ---------------------------------------------------------------------------
// k1: c1 = relu(data @ w1' + bias1), output bf16 [N,64]
// ---------------------------------------------------------------------------
__global__ __launch_bounds__(256) void k1_conv1x1a(
    const float* __restrict__ data, const unsigned short* __restrict__ w1p,
    const float* __restrict__ bias1, unsigned short* __restrict__ c1b)
{
    __shared__ short8_t w1s[2048];   // 32 KB
    int tid = threadIdx.x;
    const short8_t* wsrc = (const short8_t*)w1p;
#pragma unroll
    for (int i = 0; i < 8; i++) w1s[tid + i * 256] = wsrc[tid + i * 256];

    int lane = tid & 63, wave = tid >> 6;
    int g = lane >> 4, r = lane & 15;
    int rowbase = blockIdx.x * 128 + wave * 32;
    f32x4 acc[2][4] = {};
    __syncthreads();

#pragma unroll
    for (int s = 0; s < 8; s++) {
        short8_t a[2];
#pragma unroll
        for (int sub = 0; sub < 2; sub++) {
            const float* ap = data + (size_t)(rowbase + sub * 16 + r) * CIN + s * 32 + g * 8;
            float4 f0 = *(const float4*)ap;
            float4 f1 = *(const float4*)(ap + 4);
            short8_t av;
            av[0] = (short)f2bf(f0.x); av[1] = (short)f2bf(f0.y);
            av[2] = (short)f2bf(f0.z); av[3] = (short)f2bf(f0.w);
            av[4] = (short)f2bf(f1.x); av[5] = (short)f2bf(f1.y);
            av[6] = (short)f2bf(f1.z); av[7] = (short)f2bf(f1.w);
            a[sub] = av;
        }
#pragma unroll
        for (int t = 0; t < 4; t++) {
            short8_t b = w1s[(s * 4 + t) * 64 + lane];
            acc[0][t] = mfma16(a[0], b, acc[0][t]);
            acc[1][t] = mfma16(a[1], b, acc[1][t]);
        }
    }

#pragma unroll
    for (int sub = 0; sub < 2; sub++)
#pragma unroll
        for (int t = 0; t < 4; t++) {
            int col = t * 16 + r;
            float bs = bias1[col];
#pragma unroll
            for (int i = 0; i < 4; i++) {
                int row = rowbase + sub * 16 + g * 4 + i;
                c1b[row * CB + col] = f2bf(fmaxf(acc[sub][t][i] + bs, 0.f));
            }
        }
}

// ---------------------------------------------------------------------------
// k2: c2 = relu(sum_k c1[neigh[n,k]] @ w3'[k] + bias2), bf16 [N,64]
// Barrier-free main loop: neigh indices staged once in LDS; w3 B-frags read
// straight from L2; software pipeline depth 1 (a/b ping-pong, idx 2 ahead).
// ---------------------------------------------------------------------------
#define K2_MFMA(aX, bX) \
    _Pragma("unroll") for (int t = 0; t < 4; t++) { \
        acc[0][t] = mfma16(aX[0], bX[t],     acc[0][t]); \
        acc[1][t] = mfma16(aX[2], bX[t],     acc[1][t]); \
        acc[0][t] = mfma16(aX[1], bX[4 + t], acc[0][t]); \
        acc[1][t] = mfma16(aX[3], bX[4 + t], acc[1][t]); \
    }

// compute on (aC,bC) for step k; prefetch a/b for k+1 into (aN,bN) using
// (ixN0,ixN1); refill ixC with indices for k+2.
#define K2_BODY(aC, bC, ixC0, ixC1, aN, bN, ixN0, ixN1, k) \
    { \
        if ((k) < 26) { \
            const short8_t* p0 = (const short8_t*)(c1b + (size_t)(ixN0) * CB); \
            const short8_t* p1 = (const short8_t*)(c1b + (size_t)(ixN1) * CB); \
            aN[0] = p0[g]; aN[1] = p0[4 + g]; aN[2] = p1[g]; aN[3] = p1[4 + g]; \
            const short8_t* bp = bbase + ((k) + 1) * 512; \
            _Pragma("unroll") for (int f = 0; f < 8; f++) bN[f] = bp[f * 64 + lane]; \
        } \
        if ((k) < 25) { ixC0 = nidx[lr0 * KNB + (k) + 2]; ixC1 = nidx[lr1 * KNB + (k) + 2]; } \
        K2_MFMA(aC, bC) \
    }

__global__ __launch_bounds__(256, 3) void k2_conv3x3(
    const unsigned short* __restrict__ c1b, const int* __restrict__ neigh,
    const unsigned short* __restrict__ w3p, const float* __restrict__ bias2,
    unsigned short* __restrict__ c2b)
{
    __shared__ int nidx[128 * KNB];          // 13824 B
    int tid = threadIdx.x;
    int rowbase = blockIdx.x * 128;

    // coalesced cooperative load of this block's neighbor table
    const int4* nsrc = (const int4*)(neigh + (size_t)rowbase * KNB);
#pragma unroll
    for (int i = 0; i < 4; i++) {
        int p = tid + i * 256;
        if (p < 864) ((int4*)nidx)[p] = nsrc[p];
    }

    int lane = tid & 63, wave = tid >> 6;
    int g = lane >> 4, r = lane & 15;
    int lr0 = wave * 32 + r, lr1 = lr0 + 16;   // local row indices
    __syncthreads();

    const short8_t* bbase = (const short8_t*)w3p;
    f32x4 acc[2][4] = {};
    short8_t aA[4], aB[4], bA[8], bB[8];
    int ixA0, ixA1, ixB0, ixB1;

    // prologue: idx for k=0,1; issue a/b for k=0 into set A
    ixA0 = nidx[lr0 * KNB + 0]; ixA1 = nidx[lr1 * KNB + 0];
    ixB0 = nidx[lr0 * KNB + 1]; ixB1 = nidx[lr1 * KNB + 1];
    {
        const short8_t* p0 = (const short8_t*)(c1b + (size_t)ixA0 * CB);
        const short8_t* p1 = (const short8_t*)(c1b + (size_t)ixA1 * CB);
        aA[0] = p0[g]; aA[1] = p0[4 + g]; aA[2] = p1[g]; aA[3] = p1[4 + g];
#pragma unroll
        for (int f = 0; f < 8; f++) bA[f] = bbase[f * 64 + lane];
    }

    for (int kk = 0; kk < 13; kk++) {
        int k0 = kk * 2;
        K2_BODY(aA, bA, ixA0, ixA1, aB, bB, ixB0, ixB1, k0)
        K2_BODY(aB, bB, ixB0, ixB1, aA, bA, ixA0, ixA1, k0 + 1)
    }
    K2_BODY(aA, bA, ixA0, ixA1, aB, bB, ixB0, ixB1, 26)

#pragma unroll
    for (int sub = 0; sub < 2; sub++)
#pragma unroll
        for (int t = 0; t < 4; t++) {
            int col = t * 16 + r;
            float bs = bias2[col];
#pragma unroll
            for (int i = 0; i < 4; i++) {
                int row = rowbase + wave * 32 + sub * 16 + g * 4 + i;
                c2b[row * CB + col] = f2bf(fmaxf(acc[sub][t][i] + bs, 0.f));
            }
        }
}

// ---------------------------------------------------------------------------
// k3: out = relu(c2 @ w2' + bias3 + data), fp32 [N,256]
// 64 rows/block; MFMA -> LDS tile (stride 260) -> coalesced float4
// read-modify-write epilogue (residual + relu). w2 B-frags read from L2.
// ---------------------------------------------------------------------------
__global__ __launch_bounds__(256) void k3_conv1x1b(
    const unsigned short* __restrict__ c2b, const unsigned short* __restrict__ w2p,
    const float* __restrict__ bias3, const float* __restrict__ data,
    float* __restrict__ out)
{
    __shared__ float otile[64 * 260];        // 66560 B -> 2 blocks/CU
    int tid = threadIdx.x;
    int lane = tid & 63, wave = tid >> 6;
    int g = lane >> 4, r = lane & 15;
    int rowbase = blockIdx.x * 64;

    const short8_t* bbase = (const short8_t*)w2p;
    short8_t a[4][2];
#pragma unroll
    for (int sub = 0; sub < 4; sub++) {
        const short8_t* ap = (const short8_t*)(c2b + (size_t)(rowbase + sub * 16 + r) * CB);
        a[sub][0] = ap[g];
        a[sub][1] = ap[4 + g];
    }
    f32x4 acc[4][4] = {};
#pragma unroll
    for (int s = 0; s < 2; s++)
#pragma unroll
        for (int t = 0; t < 4; t++) {
            short8_t b = bbase[(s * 16 + wave * 4 + t) * 64 + lane];
#pragma unroll
            for (int sub = 0; sub < 4; sub++)
                acc[sub][t] = mfma16(a[sub][s], b, acc[sub][t]);
        }

    // scatter accumulators (+bias) into the LDS tile
#pragma unroll
    for (int sub = 0; sub < 4; sub++)
#pragma unroll
        for (int t = 0; t < 4; t++) {
            int col = (wave * 4 + t) * 16 + r;
            float bs = bias3[col];
#pragma unroll
            for (int i = 0; i < 4; i++) {
                int row = sub * 16 + g * 4 + i;
                otile[row * 260 + col] = acc[sub][t][i] + bs;
            }
        }
    __syncthreads();

    // coalesced residual + relu + store, float4 per lane
    const float* dsrc = data + (size_t)rowbase * CIN;
    float* dst = out + (size_t)rowbase * CIN;
#pragma unroll
    for (int p = 0; p < 16; p++) {
        int flat = p * 1024 + tid * 4;
        int row = flat >> 8, col = flat & 255;
        float4 dv = *(const float4*)(dsrc + flat);
        float4 ov = *(const float4*)(&otile[row * 260 + col]);
        float4 res;
        res.x = fmaxf(ov.x + dv.x, 0.f);
        res.y = fmaxf(ov.y + dv.y, 0.f);
        res.z = fmaxf(ov.z + dv.z, 0.f);
        res.w = fmaxf(ov.w + dv.w, 0.f);
        *(float4*)(dst + flat) = res;
    }
}

extern "C" void kernel_launch(void* const* d_in, const int* in_sizes, int n_in,
                              void* d_out, int out_size, void* d_ws, size_t ws_size,
                              hipStream_t stream)
{
    const float* data = (const float*)d_in[0];
    const int* neigh  = (const int*)d_in[1];
    const float* w1 = (const float*)d_in[3];
    const float* g1 = (const float*)d_in[4];
    const float* b1 = (const float*)d_in[5];
    const float* m1 = (const float*)d_in[6];
    const float* v1 = (const float*)d_in[7];
    const float* w3 = (const float*)d_in[8];
    const float* g2 = (const float*)d_in[9];
    const float* b2 = (const float*)d_in[10];
    const float* v2 = (const float*)d_in[12];
    const float* m2 = (const float*)d_in[11];
    const float* w2 = (const float*)d_in[13];
    const float* g3 = (const float*)d_in[14];
    const float* b3 = (const float*)d_in[15];
    const float* m3 = (const float*)d_in[16];
    const float* v3 = (const float*)d_in[17];
    float* out = (float*)d_out;

    char* ws = (char*)d_ws;
    unsigned short* c1b = (unsigned short*)ws;                              // 16 MB
    unsigned short* c2b = (unsigned short*)(ws + 16777216);                 // 16 MB
    unsigned short* w1p = (unsigned short*)(ws + 33554432);                 // 32 KB
    unsigned short* w3p = (unsigned short*)(ws + 33554432 + 32768);         // 216 KB
    unsigned short* w2p = (unsigned short*)(ws + 33554432 + 32768 + 221184);// 32 KB
    float* bias1 = (float*)(ws + 33554432 + 32768 + 221184 + 32768);
    float* bias2 = bias1 + 64;
    float* bias3 = bias1 + 128;

    int n = in_sizes[0] / CIN;   // 131072

    hipLaunchKernelGGL(prep_kernel, dim3(562), dim3(256), 0, stream,
                       w1, w3, w2, g1, b1, m1, v1, g2, b2, m2, v2, g3, b3, m3, v3,
                       w1p, w3p, w2p, bias1, bias2, bias3);
    hipLaunchKernelGGL(k1_conv1x1a, dim3(n / 128), dim3(256), 0, stream, data, w1p, bias1, c1b);
    hipLaunchKernelGGL(k2_conv3x3,  dim3(n / 128), dim3(256), 0, stream, c1b, neigh, w3p, bias2, c2b);
    hipLaunchKernelGGL(k3_conv1x1b, dim3(n / 64),  dim3(256), 0, stream, c2b, w2p, bias3, data, out);
}